// Round 9
// baseline (104.410 us; speedup 1.0000x reference)
//
#include <hip/hip_runtime.h>

typedef __attribute__((ext_vector_type(4))) float f32x4;
typedef __attribute__((ext_vector_type(8))) short bf16x8;
typedef __attribute__((ext_vector_type(4))) unsigned int u32x4;

#define IDIM    128
#define HID     64
#define TDEPTH  6
#define WROWS   32                       // rows per wave
#define NWAVES  4
#define BLOCK   (NWAVES * 64)            // 256
#define MROWS   (WROWS * NWAVES)         // 128 rows per block
#define NODE_ELEMS 8192                  // shorts per node B-fragment slice (16 KB)
#define WFRAG_ELEMS (TDEPTH * NODE_ELEMS)

__device__ __forceinline__ unsigned short f2bf(float f) {
    unsigned int u = __builtin_bit_cast(unsigned int, f);
    unsigned int r = (u + 0x7FFFu + ((u >> 16) & 1u)) >> 16;  // RNE
    return (unsigned short)r;
}

__device__ __forceinline__ unsigned int f2bf_pk(float f0, float f1) {
    unsigned int u0 = __builtin_bit_cast(unsigned int, f0);
    unsigned int u1 = __builtin_bit_cast(unsigned int, f1);
    unsigned int t0 = u0 + 0x7FFFu + ((u0 >> 16) & 1u);
    unsigned int t1 = u1 + 0x7FFFu + ((u1 >> 16) & 1u);
    return (t1 & 0xFFFF0000u) | (t0 >> 16);
}

// Pre-convert W1 (6 chain nodes) into bf16 MFMA B-fragment layout, node-major.
// B-frag: lane holds B[k=(lane>>4)*8+j][n=lane&15]. Workspace use is free (the
// harness's 268 MB poison fill runs unconditionally every iteration).
__global__ void prep_wfrag(const float* __restrict__ W1, unsigned short* __restrict__ wfrag) {
    int idx = blockIdx.x * 256 + threadIdx.x;
    if (idx >= WFRAG_ELEMS) return;
    int j    = idx & 7;
    int lane = (idx >> 3) & 63;
    int ct   = (idx >> 9) & 3;
    int ks   = (idx >> 11) & 3;
    int nd   = idx >> 13;
    int node = (1 << nd) - 1;              // chain node: 0,1,3,7,15,31
    int k    = ks * 32 + (lane >> 4) * 8 + j;
    int col  = ct * 16 + (lane & 15);
    wfrag[idx] = f2bf(W1[(node * IDIM + k) * HID + col]);
}

// Round-9 = Round-7 structure (best measured: ~32us kernel) with ONE change:
// NON-TEMPORAL x loads. Session model: the 268 MB poison fill immediately
// before this kernel leaves L2/L3 full of DIRTY lines; every x read-miss must
// evict a dirty victim (writeback) -> read latency+traffic inflate, kernel
// runs at ~1 TB/s vs the fill's own 6.25 TB/s in the same stream (R6 PMC:
// 345 GB/s, FETCH=half of x, latency-bound). nt loads don't allocate -> no
// victim writeback on the critical path; leftover L3 x-hits still hit.
// out stored nt as well (never re-read; don't create new dirty lines).
template <bool USE_WS>
__global__ __launch_bounds__(BLOCK, 3)
void sdt_kernel(const float* __restrict__ x, const float* __restrict__ W1,
                const float* __restrict__ b1, const float* __restrict__ W2,
                const float* __restrict__ b2, const float* __restrict__ leaf,
                const unsigned short* __restrict__ wfrag, float* __restrict__ out) {
    __shared__ __align__(16) unsigned short bs[2][NODE_ELEMS];  // 32 KB
    __shared__ float p_lds[NWAVES][WROWS][8];                   // [..][nd]
    __shared__ float leaf_lds[64];

    const int tid  = threadIdx.x;
    const int wave = tid >> 6;
    const int lane = tid & 63;
    const int lcol = lane & 15;
    const int lq   = lane >> 4;
    const int m0   = blockIdx.x * MROWS + wave * WROWS;

    // ---- A: this wave's 32 rows, straight from HBM, one nt burst ----
    // A-frag target: lane holds A[row = rt*16 + lcol][k = ks*32 + lq*8 + j]
    const float* xb = x + (size_t)(m0 + lcol) * IDIM + lq * 8;
    f32x4 araw[2][4][2];
    #pragma unroll
    for (int rt = 0; rt < 2; rt++)
        #pragma unroll
        for (int ks = 0; ks < 4; ks++) {
            const f32x4* ap = reinterpret_cast<const f32x4*>(
                xb + (size_t)(rt * 16) * IDIM + ks * 32);
            araw[rt][ks][0] = __builtin_nontemporal_load(ap);
            araw[rt][ks][1] = __builtin_nontemporal_load(ap + 1);
        }

    // ---- stage node-0 B fragment + leaf while A loads are in flight ----
    auto stage = [&](int buf, int nd) {
        if (USE_WS) {
            const u32x4* src = reinterpret_cast<const u32x4*>(wfrag + nd * NODE_ELEMS);
            u32x4* dst = reinterpret_cast<u32x4*>(&bs[buf][0]);
            #pragma unroll
            for (int i = 0; i < (NODE_ELEMS * 2 / 16) / BLOCK; i++)   // 4
                dst[tid + i * BLOCK] = src[tid + i * BLOCK];
        } else {
            int node = (1 << nd) - 1;
            for (int e = tid; e < NODE_ELEMS; e += BLOCK) {
                int j = e & 7, ln = (e >> 3) & 63, ct = (e >> 9) & 3, ks = e >> 11;
                int k   = ks * 32 + (ln >> 4) * 8 + j;
                int col = ct * 16 + (ln & 15);
                bs[buf][e] = f2bf(W1[((size_t)node * IDIM + k) * HID + col]);
            }
        }
    };
    stage(0, 0);
    if (tid < 64) leaf_lds[tid] = leaf[tid];

    // ---- convert A to bf16 fragments (held for all 6 nodes) ----
    bf16x8 afrag[2][4];
    #pragma unroll
    for (int rt = 0; rt < 2; rt++)
        #pragma unroll
        for (int ks = 0; ks < 4; ks++) {
            f32x4 v0 = araw[rt][ks][0], v1 = araw[rt][ks][1];
            u32x4 pk;
            pk[0] = f2bf_pk(v0.x, v0.y);
            pk[1] = f2bf_pk(v0.z, v0.w);
            pk[2] = f2bf_pk(v1.x, v1.y);
            pk[3] = f2bf_pk(v1.z, v1.w);
            afrag[rt][ks] = __builtin_bit_cast(bf16x8, pk);
        }

    __syncthreads();                        // bs[0] + leaf ready

    #pragma unroll
    for (int nd = 0; nd < TDEPTH; nd++) {
        const int buf = nd & 1;
        if (nd + 1 < TDEPTH) stage(buf ^ 1, nd + 1);   // prefetch next node's B

        const int node = (1 << nd) - 1;
        float b1v[4], w2v[4];
        #pragma unroll
        for (int ct = 0; ct < 4; ct++) {
            int col = ct * 16 + lcol;
            b1v[ct] = b1[node * HID + col];
            w2v[ct] = W2[node * HID + col];
        }
        const float bias2 = b2[node];

        // ---- GEMM: 32 rows x 64 cols, K=128; B from LDS ----
        f32x4 acc[2][4];
        #pragma unroll
        for (int rt = 0; rt < 2; rt++)
            #pragma unroll
            for (int ct = 0; ct < 4; ct++)
                acc[rt][ct] = (f32x4){0.f, 0.f, 0.f, 0.f};
        #pragma unroll
        for (int ks = 0; ks < 4; ks++) {
            bf16x8 bfrag[4];
            #pragma unroll
            for (int ct = 0; ct < 4; ct++)
                bfrag[ct] = *reinterpret_cast<const bf16x8*>(
                    &bs[buf][(ks * 4 + ct) * 512 + lane * 8]);
            #pragma unroll
            for (int rt = 0; rt < 2; rt++)
                #pragma unroll
                for (int ct = 0; ct < 4; ct++)
                    acc[rt][ct] = __builtin_amdgcn_mfma_f32_16x16x32_bf16(
                        afrag[rt][ks], bfrag[ct], acc[rt][ct], 0, 0, 0);
        }

        // ---- epilogue: relu, dot W2, sigmoid -> p_lds ----
        // C layout: col = ct*16 + lcol, row = rt*16 + lq*4 + r
        #pragma unroll
        for (int rt = 0; rt < 2; rt++) {
            #pragma unroll
            for (int r = 0; r < 4; r++) {
                float s = 0.f;
                #pragma unroll
                for (int ct = 0; ct < 4; ct++) {
                    float v = acc[rt][ct][r] + b1v[ct];
                    v = v > 0.f ? v : 0.f;
                    s += v * w2v[ct];
                }
                #pragma unroll
                for (int d = 1; d < 16; d <<= 1)
                    s += __shfl_xor(s, d, 64);
                float p = 1.f / (1.f + __expf(-(s + bias2)));
                if (lcol == 0)
                    p_lds[wave][rt * 16 + lq * 4 + r][nd] = p;
            }
        }
        __syncthreads();   // bs[buf^1] staged; p_lds(nd) done; bs[buf] free
    }

    // ---- fold: 128 threads, one per row ----
    if (tid < MROWS) {
        const int wv = tid >> 5, row = tid & 31;
        float q0 = p_lds[wv][row][0];
        float q1 = p_lds[wv][row][1];
        float q2 = p_lds[wv][row][2];
        float q3 = p_lds[wv][row][3];
        float p4 = p_lds[wv][row][4];
        float p5 = p_lds[wv][row][5];
        float acc_out = 0.f;
        #pragma unroll
        for (int ch = 0; ch < 4; ch++) {
            float f4 = (ch & 1) ? p4 : 1.f - p4;
            float f5 = (ch & 2) ? p5 : 1.f - p5;
            const float* lf = leaf_lds + ch * 16;
            float tt[8];
            #pragma unroll
            for (int j = 0; j < 8; j++) {
                float a = lf[2 * j], b = lf[2 * j + 1];
                tt[j] = a + q0 * (b - a);
            }
            #pragma unroll
            for (int j = 0; j < 4; j++) tt[j] = tt[2 * j] + q1 * (tt[2 * j + 1] - tt[2 * j]);
            #pragma unroll
            for (int j = 0; j < 2; j++) tt[j] = tt[2 * j] + q2 * (tt[2 * j + 1] - tt[2 * j]);
            float s = tt[0] + q3 * (tt[1] - tt[0]);
            acc_out += f4 * f5 * s;
        }
        __builtin_nontemporal_store(acc_out, out + (size_t)blockIdx.x * MROWS + tid);
    }
}

extern "C" void kernel_launch(void* const* d_in, const int* in_sizes, int n_in,
                              void* d_out, int out_size, void* d_ws, size_t ws_size,
                              hipStream_t stream) {
    const float* x    = (const float*)d_in[0];
    const float* W1   = (const float*)d_in[1];
    const float* b1   = (const float*)d_in[2];
    const float* W2   = (const float*)d_in[3];
    const float* b2   = (const float*)d_in[4];
    const float* leaf = (const float*)d_in[5];
    float* out = (float*)d_out;

    const int Bn = in_sizes[0] / IDIM;               // 65536 rows
    const int nblocks = Bn / MROWS;                  // 512 — entire grid resident

    if (ws_size >= (size_t)WFRAG_ELEMS * sizeof(unsigned short)) {
        unsigned short* wfrag = (unsigned short*)d_ws;
        prep_wfrag<<<(WFRAG_ELEMS + 255) / 256, 256, 0, stream>>>(W1, wfrag);
        sdt_kernel<true><<<nblocks, BLOCK, 0, stream>>>(x, W1, b1, W2, b2, leaf, wfrag, out);
    } else {
        sdt_kernel<false><<<nblocks, BLOCK, 0, stream>>>(x, W1, b1, W2, b2, leaf, nullptr, out);
    }
}

// Round 10
// 92.648 us; speedup vs baseline: 1.1270x; 1.1270x over previous
//
#include <hip/hip_runtime.h>

typedef __attribute__((ext_vector_type(4))) float f32x4;
typedef __attribute__((ext_vector_type(8))) short bf16x8;
typedef __attribute__((ext_vector_type(4))) unsigned int u32x4;

#define IDIM    128
#define HID     64
#define TDEPTH  6
#define WROWS   32                       // rows per wave
#define NWAVES  8
#define BLOCK   (NWAVES * 64)            // 512
#define MROWS   (WROWS * NWAVES)         // 256 rows per block
#define NODE_ELEMS 8192                  // shorts per node A-fragment slice (16 KB)
#define WFRAG_ELEMS (TDEPTH * NODE_ELEMS)

__device__ __forceinline__ unsigned short f2bf(float f) {
    unsigned int u = __builtin_bit_cast(unsigned int, f);
    unsigned int r = (u + 0x7FFFu + ((u >> 16) & 1u)) >> 16;  // RNE
    return (unsigned short)r;
}

__device__ __forceinline__ unsigned int f2bf_pk(float f0, float f1) {
    unsigned int u0 = __builtin_bit_cast(unsigned int, f0);
    unsigned int u1 = __builtin_bit_cast(unsigned int, f1);
    unsigned int t0 = u0 + 0x7FFFu + ((u0 >> 16) & 1u);
    unsigned int t1 = u1 + 0x7FFFu + ((u1 >> 16) & 1u);
    return (t1 & 0xFFFF0000u) | (t0 >> 16);
}

// Pre-convert W1 (6 chain nodes) into bf16 MFMA **A**-fragment layout of W1^T
// (swapped-GEMM: C[hid,brow] = W1T . xT). A-frag: lane holds
// A[m = ht*16 + (lane&15)][k = ks*32 + (lane>>4)*8 + j] = W1[node][k][hid].
// In-node order: (ht, ks) -> offset (ht*4+ks)*512 + lane*8 + j.
__global__ void prep_wfrag(const float* __restrict__ W1, unsigned short* __restrict__ wfrag) {
    int idx = blockIdx.x * 256 + threadIdx.x;
    if (idx >= WFRAG_ELEMS) return;
    int j    = idx & 7;
    int lane = (idx >> 3) & 63;
    int ks   = (idx >> 9) & 3;
    int ht   = (idx >> 11) & 3;
    int nd   = idx >> 13;
    int node = (1 << nd) - 1;              // chain node: 0,1,3,7,15,31
    int k    = ks * 32 + (lane >> 4) * 8 + j;
    int hid  = ht * 16 + (lane & 15);
    wfrag[idx] = f2bf(W1[((size_t)node * IDIM + k) * HID + hid]);
}

// Round-10: SWAPPED-OPERAND GEMM (reduction axis made lane-local, T12 idea).
//   C[hid, brow] = W1T x xT: A = W1T frags (from ws), B = x frags (register
//   contents + addresses BIT-IDENTICAL to the old A-frags; only the operand
//   slot changed). Lane then holds h[brow=lane&15][hid = ht*16+lq*4+r]:
//   W2-dot = 16 in-lane FMAs + 2 shfl_xor (was 4-level chain x 8 scalars),
//   p stays in regs -> fold fully in-lane, p_lds + fold barrier GONE.
//   Per wave: 192 shfl -> 24; sigmoids 48 -> 12.
// All 6 nodes' A-frags staged ONCE (96 KB LDS, R8 scheme) -> node loop has no
// staging, can fully unroll (static pq[] indexing, rule #20) with no round-5
// LICM hazard. One barrier total. 1 block/CU (R8 showed parity with 2/CU).
template <bool USE_WS>
__global__ __launch_bounds__(BLOCK, 2)
void sdt_kernel(const float* __restrict__ x, const float* __restrict__ W1,
                const float* __restrict__ b1, const float* __restrict__ W2,
                const float* __restrict__ b2, const float* __restrict__ leaf,
                const unsigned short* __restrict__ wfrag, float* __restrict__ out) {
    __shared__ __align__(16) unsigned short bs[TDEPTH * NODE_ELEMS];  // 96 KB
    __shared__ float b1s[TDEPTH][HID];
    __shared__ float w2s[TDEPTH][HID];
    __shared__ float b2s[8];
    __shared__ float leaf_lds[64];

    const int tid  = threadIdx.x;
    const int wave = tid >> 6;
    const int lane = tid & 63;
    const int lcol = lane & 15;
    const int lq   = lane >> 4;
    const int m0   = blockIdx.x * MROWS + wave * WROWS;

    // ---- x B-frags: lane holds x[m0 + bg*16 + lcol][ks*32 + lq*8 + j] ----
    // (identical addresses to the proven R7 A-path; one burst, held in regs)
    const float* xb = x + (size_t)(m0 + lcol) * IDIM + lq * 8;
    float4 araw[2][4][2];
    #pragma unroll
    for (int bg = 0; bg < 2; bg++)
        #pragma unroll
        for (int ks = 0; ks < 4; ks++) {
            const float4* ap = reinterpret_cast<const float4*>(
                xb + (size_t)(bg * 16) * IDIM + ks * 32);
            araw[bg][ks][0] = ap[0];
            araw[bg][ks][1] = ap[1];
        }

    // ---- stage ALL 6 nodes' W1T A-frags (96 KB) while x loads fly ----
    if (USE_WS) {
        const u32x4* src = reinterpret_cast<const u32x4*>(wfrag);
        u32x4* dst = reinterpret_cast<u32x4*>(&bs[0]);
        #pragma unroll
        for (int i = 0; i < (WFRAG_ELEMS * 2 / 16) / BLOCK; i++)   // 12
            dst[tid + i * BLOCK] = src[tid + i * BLOCK];
    } else {
        for (int e = tid; e < WFRAG_ELEMS; e += BLOCK) {
            int j = e & 7, ln = (e >> 3) & 63, ks = (e >> 9) & 3,
                ht = (e >> 11) & 3, nd = e >> 13;
            int node = (1 << nd) - 1;
            int k    = ks * 32 + (ln >> 4) * 8 + j;
            int hid  = ht * 16 + (ln & 15);
            bs[e] = f2bf(W1[((size_t)node * IDIM + k) * HID + hid]);
        }
    }
    // epilogue params + leaf
    for (int i = tid; i < TDEPTH * HID; i += BLOCK) {
        int nd = i >> 6, col = i & 63, node = (1 << nd) - 1;
        b1s[nd][col] = b1[node * HID + col];
        w2s[nd][col] = W2[node * HID + col];
    }
    if (tid < 6)  b2s[tid] = b2[(1 << tid) - 1];
    if (tid < 64) leaf_lds[tid] = leaf[tid];

    // ---- convert x to bf16 B-frags ----
    bf16x8 xfrag[2][4];
    #pragma unroll
    for (int bg = 0; bg < 2; bg++)
        #pragma unroll
        for (int ks = 0; ks < 4; ks++) {
            float4 v0 = araw[bg][ks][0], v1 = araw[bg][ks][1];
            u32x4 pk;
            pk[0] = f2bf_pk(v0.x, v0.y);
            pk[1] = f2bf_pk(v0.z, v0.w);
            pk[2] = f2bf_pk(v1.x, v1.y);
            pk[3] = f2bf_pk(v1.z, v1.w);
            xfrag[bg][ks] = __builtin_bit_cast(bf16x8, pk);
        }

    __syncthreads();                       // the block's ONLY barrier

    float pq[2][TDEPTH];                   // p per brow-group per node (static idx)

    #pragma unroll
    for (int nd = 0; nd < TDEPTH; nd++) {
        // ---- swapped GEMM: C[hid, brow], K=128; A(W1T) from LDS ----
        f32x4 acc[2][4];                   // [bg][ht]
        #pragma unroll
        for (int bg = 0; bg < 2; bg++)
            #pragma unroll
            for (int ht = 0; ht < 4; ht++)
                acc[bg][ht] = (f32x4){0.f, 0.f, 0.f, 0.f};
        #pragma unroll
        for (int ks = 0; ks < 4; ks++) {
            bf16x8 awf[4];
            #pragma unroll
            for (int ht = 0; ht < 4; ht++)
                awf[ht] = *reinterpret_cast<const bf16x8*>(
                    &bs[(nd * 16 + ht * 4 + ks) * 512 + lane * 8]);
            #pragma unroll
            for (int bg = 0; bg < 2; bg++)
                #pragma unroll
                for (int ht = 0; ht < 4; ht++)
                    acc[bg][ht] = __builtin_amdgcn_mfma_f32_16x16x32_bf16(
                        awf[ht], xfrag[bg][ks], acc[bg][ht], 0, 0, 0);
        }

        // ---- epilogue: lane holds h[brow=bg*16+lcol][hid=ht*16+lq*4+r] ----
        f32x4 b1q[4], w2q[4];
        #pragma unroll
        for (int ht = 0; ht < 4; ht++) {
            b1q[ht] = *reinterpret_cast<const f32x4*>(&b1s[nd][ht * 16 + lq * 4]);
            w2q[ht] = *reinterpret_cast<const f32x4*>(&w2s[nd][ht * 16 + lq * 4]);
        }
        const float bias2 = b2s[nd];
        #pragma unroll
        for (int bg = 0; bg < 2; bg++) {
            float s = 0.f;
            #pragma unroll
            for (int ht = 0; ht < 4; ht++)
                #pragma unroll
                for (int r = 0; r < 4; r++) {
                    float v = acc[bg][ht][r] + b1q[ht][r];
                    v = v > 0.f ? v : 0.f;
                    s += v * w2q[ht][r];
                }
            s += __shfl_xor(s, 16, 64);    // combine the 4 lq groups
            s += __shfl_xor(s, 32, 64);
            pq[bg][nd] = 1.f / (1.f + __expf(-(s + bias2)));
        }
    }

    // ---- fold: fully in-lane (p in regs; leaf via LDS broadcast) ----
    #pragma unroll
    for (int bg = 0; bg < 2; bg++) {
        float q0 = pq[bg][0], q1 = pq[bg][1], q2 = pq[bg][2];
        float q3 = pq[bg][3], p4 = pq[bg][4], p5 = pq[bg][5];
        float acc_out = 0.f;
        #pragma unroll
        for (int ch = 0; ch < 4; ch++) {
            float f4 = (ch & 1) ? p4 : 1.f - p4;
            float f5 = (ch & 2) ? p5 : 1.f - p5;
            const float* lf = leaf_lds + ch * 16;
            float tt[8];
            #pragma unroll
            for (int j = 0; j < 8; j++) {
                float a = lf[2 * j], b = lf[2 * j + 1];
                tt[j] = a + q0 * (b - a);
            }
            #pragma unroll
            for (int j = 0; j < 4; j++) tt[j] = tt[2 * j] + q1 * (tt[2 * j + 1] - tt[2 * j]);
            #pragma unroll
            for (int j = 0; j < 2; j++) tt[j] = tt[2 * j] + q2 * (tt[2 * j + 1] - tt[2 * j]);
            float s = tt[0] + q3 * (tt[1] - tt[0]);
            acc_out += f4 * f5 * s;
        }
        if (lq == 0)                        // lanes 0-15: coalesced 64B store
            out[(size_t)m0 + bg * 16 + lcol] = acc_out;
    }
}

extern "C" void kernel_launch(void* const* d_in, const int* in_sizes, int n_in,
                              void* d_out, int out_size, void* d_ws, size_t ws_size,
                              hipStream_t stream) {
    const float* x    = (const float*)d_in[0];
    const float* W1   = (const float*)d_in[1];
    const float* b1   = (const float*)d_in[2];
    const float* W2   = (const float*)d_in[3];
    const float* b2   = (const float*)d_in[4];
    const float* leaf = (const float*)d_in[5];
    float* out = (float*)d_out;

    const int Bn = in_sizes[0] / IDIM;               // 65536 rows
    const int nblocks = Bn / MROWS;                  // 256 — 1 block/CU

    if (ws_size >= (size_t)WFRAG_ELEMS * sizeof(unsigned short)) {
        unsigned short* wfrag = (unsigned short*)d_ws;
        prep_wfrag<<<(WFRAG_ELEMS + 255) / 256, 256, 0, stream>>>(W1, wfrag);
        sdt_kernel<true><<<nblocks, BLOCK, 0, stream>>>(x, W1, b1, W2, b2, leaf, wfrag, out);
    } else {
        sdt_kernel<false><<<nblocks, BLOCK, 0, stream>>>(x, W1, b1, W2, b2, leaf, nullptr, out);
    }
}